// Round 10
// baseline (246.922 us; speedup 1.0000x reference)
//
#include <hip/hip_runtime.h>
#include <hip/hip_bf16.h>

// MHA: B=2, T=2048, C=1024, H=16, Dh=64. fp32 in/out, bf16 MFMA internally.
// ws layout (bf16 elems): [0,4M): xb. [4M,7M): wq|wk|wv. [7M,8M): wo.
// [8M,12M): Q. [12M,16M): K. [16M,20M): Vt (written by QKV gemm epilogue).
// [20M,24M): AO.  Total 48 MB.

typedef __bf16 bf16;
typedef __attribute__((ext_vector_type(8))) __bf16 bf16x8;
typedef __attribute__((ext_vector_type(4))) __bf16 bf16x4;
typedef __attribute__((ext_vector_type(4))) float floatx4;
typedef __attribute__((ext_vector_type(4))) short short4v;

#define LOG2E 1.44269504088896340736f

__device__ __forceinline__ void gl2lds16(const void* g, void* l) {
  __builtin_amdgcn_global_load_lds((const __attribute__((address_space(1))) void*)g,
                                   (__attribute__((address_space(3))) void*)l, 16, 0, 0);
}

// 16x16x16 bf16 MFMA (k=16): B-operand layout (n=l15, k=l4*4+i) matches the
// 16x16 C/D layout exactly -> lets P stay in registers.
__device__ __forceinline__ floatx4 mfma16(bf16x4 a, bf16x4 b, floatx4 c) {
#if __has_builtin(__builtin_amdgcn_mfma_f32_16x16x16_bf16)
  return __builtin_amdgcn_mfma_f32_16x16x16_bf16(a, b, c, 0, 0, 0);
#elif __has_builtin(__builtin_amdgcn_mfma_f32_16x16x16bf16_1k)
  return __builtin_amdgcn_mfma_f32_16x16x16bf16_1k(
      __builtin_bit_cast(short4v, a), __builtin_bit_cast(short4v, b), c, 0, 0, 0);
#else
  floatx4 d = c;
  asm volatile("v_mfma_f32_16x16x16_bf16 %0, %1, %2, %0"
               : "+v"(d) : "v"(a), "v"(b));
  return d;
#endif
}

// ---------------- cast fp32 -> bf16 (x | wq | wk | wv | wo) ----------------
__global__ __launch_bounds__(256) void cast_all(
    const float* __restrict__ x, const float* __restrict__ wq,
    const float* __restrict__ wk, const float* __restrict__ wv,
    const float* __restrict__ wo, bf16* __restrict__ dst)
{
  const size_t M1 = (size_t)1 << 20;
  size_t i4 = ((size_t)blockIdx.x * 256 + threadIdx.x) * 4;
  const float* src = x;
  size_t off = i4;
  if (i4 >= 4 * M1) {
    size_t r = i4 - 4 * M1;
    int seg = (int)(r >> 20);
    off = r & (M1 - 1);
    src = (seg == 0) ? wq : (seg == 1) ? wk : (seg == 2) ? wv : wo;
  }
  float4 f = *(const float4*)(src + off);
  bf16x4 o = { (bf16)f.x, (bf16)f.y, (bf16)f.z, (bf16)f.w };
  *(bf16x4*)(dst + i4) = o;
}

// ---------------- GEMM: out[m][n] = sum_k A[m][k]*W[n][k] + bias[n] ----------------
// BK=64, xor-swizzled 16B LDS groups, 32 MFMA/barrier.
// QKV: mat0 -> Q (bf16, pre-scaled), mat1 -> K, mat2 -> Vt[bh][d][t].
template<bool F32OUT, bool QKV, int BN>
__global__ __launch_bounds__(256, 3) void gemm_bt(
    const bf16* __restrict__ A, const bf16* __restrict__ Wb,
    const float* __restrict__ bq, const float* __restrict__ bk,
    const float* __restrict__ bv, void* __restrict__ outb,
    bf16* __restrict__ vt, int M, int N, int K, float qscale)
{
  __shared__ bf16 As[128 * 64];
  __shared__ bf16 Bs[BN * 64];
  const int tid = threadIdx.x;
  const int lane = tid & 63;
  const int wid = tid >> 6;
  const int l15 = lane & 15, l4 = lane >> 4;
  constexpr int I = (BN == 128) ? 4 : 2;
  const int wr = (BN == 128) ? (wid >> 1) : wid;
  const int wc = (BN == 128) ? (wid & 1) : 0;

  const bf16* W;
  const float* bias;
  float osc = 1.0f;
  int n0, mat = 0;
  bf16* outh;
  float* outf;
  if (QKV) {
    mat = blockIdx.x >> 3;
    n0 = (blockIdx.x & 7) << 7;
    W = Wb + ((size_t)mat << 20);
    bias = (mat == 0) ? bq : (mat == 1 ? bk : bv);
    if (mat == 0) osc = qscale;
    outh = (bf16*)outb + ((size_t)mat << 22);
    outf = nullptr;
  } else {
    n0 = blockIdx.x * BN;
    W = Wb;
    bias = bq;
    outf = (float*)outb;
    outh = nullptr;
  }
  const int m0 = blockIdx.y << 7;

  floatx4 acc[I][4] = {};

  for (int k0 = 0; k0 < K; k0 += 64) {
#pragma unroll
    for (int it = 0; it < 4; ++it) {
      int c = it * 256 + tid;
      int row = c >> 3, gs = ((c & 7) ^ (row & 7)) << 3;
      gl2lds16(A + (size_t)(m0 + row) * K + k0 + gs, As + c * 8);
    }
#pragma unroll
    for (int it = 0; it < BN / 32; ++it) {
      int c = it * 256 + tid;
      int row = c >> 3, gs = ((c & 7) ^ (row & 7)) << 3;
      gl2lds16(W + (size_t)(n0 + row) * K + k0 + gs, Bs + c * 8);
    }
    __syncthreads();
#pragma unroll
    for (int kk = 0; kk < 2; ++kk) {
      bf16x8 af[I], bfr[4];
#pragma unroll
      for (int i = 0; i < I; ++i) {
        int r = wr * (I * 16) + i * 16 + l15;
        int g = (kk * 4 + l4) ^ (r & 7);
        af[i] = *(const bf16x8*)(As + r * 64 + g * 8);
      }
#pragma unroll
      for (int j = 0; j < 4; ++j) {
        int r = wc * 64 + j * 16 + l15;
        int g = (kk * 4 + l4) ^ (r & 7);
        bfr[j] = *(const bf16x8*)(Bs + r * 64 + g * 8);
      }
#pragma unroll
      for (int i = 0; i < I; ++i)
#pragma unroll
        for (int j = 0; j < 4; ++j)
          acc[i][j] = __builtin_amdgcn_mfma_f32_16x16x32_bf16(af[i], bfr[j], acc[i][j], 0, 0, 0);
    }
    __syncthreads();
  }

  if (QKV && mat == 2) {
#pragma unroll
    for (int j = 0; j < 4; ++j) {
      int col = n0 + wc * 64 + j * 16 + l15;
      float bv_ = bias[col];
      int h = col >> 6, d = col & 63;
#pragma unroll
      for (int i = 0; i < I; ++i) {
        int row = m0 + wr * (I * 16) + i * 16 + l4 * 4;
        int bb = row >> 11, t = row & 2047;
        bf16x4 pk;
#pragma unroll
        for (int rg = 0; rg < 4; ++rg) pk[rg] = (bf16)(acc[i][j][rg] + bv_);
        *(bf16x4*)(vt + (((size_t)(bb * 16 + h)) << 17) + ((size_t)d << 11) + t) = pk;
      }
    }
    return;
  }

#pragma unroll
  for (int j = 0; j < 4; ++j) {
    int col = n0 + wc * 64 + j * 16 + l15;
    float bv_ = bias[col];
#pragma unroll
    for (int i = 0; i < I; ++i) {
#pragma unroll
      for (int rg = 0; rg < 4; ++rg) {
        int row = m0 + wr * (I * 16) + i * 16 + l4 * 4 + rg;
        float v = (acc[i][j][rg] + bv_) * osc;
        if (F32OUT) outf[(size_t)row * N + col] = v;
        else        outh[(size_t)row * N + col] = (bf16)v;
      }
    }
  }
}

// ---------------- wave-autonomous causal flash attention ----------------
// grid 2048 x 64 threads: ONE WAVE PER BLOCK, no __syncthreads anywhere.
// bh = u&31 (head-local L2/XCD), qc = 63-(u>>5) (heavy first). Wave owns
// 32 q-rows (Q B-frags in registers), iterates 16-j K/V strips with
// per-wave double-buffered gl2lds staging + explicit s_waitcnt vmcnt.
// S^T (col q = l15) -> per-lane softmax; PV via 16x16x16 MFMA whose
// B-layout equals the S^T C-layout -> P STAYS IN REGISTERS (no LDS P).
// LDS 8 KB/block -> ~16 waves/CU. Q pre-scaled by 1/sqrt(Dh)*log2e.
__global__ __launch_bounds__(64, 4) void attn_kernel(
    const bf16* __restrict__ Q, const bf16* __restrict__ Kg,
    const bf16* __restrict__ Vt, bf16* __restrict__ AO)
{
  constexpr int T = 2048, C = 1024;
  __shared__ bf16 Ks[2][16 * 64];   // [j][d], 16B groups xor'd by (j&7)
  __shared__ bf16 Vts[2][64 * 16];  // [d][j], 16B halves xor'd by ((d>>2)&1)

  const int lane = threadIdx.x;
  const int l15 = lane & 15, l4 = lane >> 4;

  const int u = blockIdx.x;
  const int bh = u & 31;
  const int qc = 63 - (u >> 5);            // 0..63, heavy first
  const int qw = qc << 5;                  // 32 q-rows per wave
  const int ns = 2 * qc + 2;               // 16-j strips
  const size_t base = ((size_t)(bh >> 4) * T) * C + (bh & 15) * 64;
  const bf16* vtb = Vt + ((size_t)bh << 17);

  auto stageK = [&](int j0, int bufi) {
#pragma unroll
    for (int i = 0; i < 2; ++i) {
      int c = i * 64 + lane;
      int row = c >> 3, g = (c & 7) ^ (row & 7);
      gl2lds16(Kg + base + (size_t)(j0 + row) * C + g * 8, &Ks[bufi][c * 8]);
    }
  };
  auto stageV = [&](int j0, int bufi) {
#pragma unroll
    for (int i = 0; i < 2; ++i) {
      int c = i * 64 + lane;
      int d = c >> 1, h = c & 1;
      int gh = h ^ ((d >> 2) & 1);
      gl2lds16(vtb + ((size_t)d << 11) + j0 + gh * 8, &Vts[bufi][c * 8]);
    }
  };

  // Q B-frags: q = qw + tq*16 + l15, k(d) = kk*32 + l4*8
  bf16x8 qf[2][2];
#pragma unroll
  for (int tq = 0; tq < 2; ++tq) {
    const bf16* qp = Q + base + (size_t)(qw + tq * 16 + l15) * C + l4 * 8;
    qf[tq][0] = *(const bf16x8*)(qp);
    qf[tq][1] = *(const bf16x8*)(qp + 32);
  }

  floatx4 o[2][4] = {};                    // O^T: col q=l15, row d=td*16+l4*4+rg
  float mrow[2] = {-1e38f, -1e38f};
  float lrow[2] = {0.f, 0.f};

  stageK(0, 0);
  stageV(0, 0);

  int buf = 0;
  for (int s = 0; s < ns; ++s) {
    __builtin_amdgcn_sched_barrier(0);
    const bool more = (s + 1 < ns);
    if (more) {
      stageK((s + 1) << 4, buf ^ 1);
      stageV((s + 1) << 4, buf ^ 1);
      __builtin_amdgcn_s_waitcnt(0x0F74);  // vmcnt(4): strip s staged, s+1 in flight
    } else {
      __builtin_amdgcn_s_waitcnt(0x0F70);  // vmcnt(0)
    }
    __builtin_amdgcn_sched_barrier(0);

    const int j0 = s << 4;

    // ---- S^T strip = K(16j) . Q^T : s4[tq], row j = l4*4+rg, col q = l15
    floatx4 s4[2] = {};
#pragma unroll
    for (int kk = 0; kk < 2; ++kk) {
      bf16x8 kf = *(const bf16x8*)(&Ks[buf][l15 * 64 + (((kk * 4 + l4) ^ (l15 & 7)) * 8)]);
      s4[0] = __builtin_amdgcn_mfma_f32_16x16x32_bf16(kf, qf[0][kk], s4[0], 0, 0, 0);
      s4[1] = __builtin_amdgcn_mfma_f32_16x16x32_bf16(kf, qf[1][kk], s4[1], 0, 0, 0);
    }

    // ---- causal mask (j > q): only the top 1-2 strips
    if (j0 + 15 > qw) {
      int j = j0 + l4 * 4;
#pragma unroll
      for (int tq = 0; tq < 2; ++tq) {
        int q = qw + tq * 16 + l15;
#pragma unroll
        for (int rg = 0; rg < 4; ++rg)
          if (j + rg > q) s4[tq][rg] = -3e38f;
      }
    }

    // ---- online softmax: lane owns row q; 2+2 shuffles per tq
    float al[2];
#pragma unroll
    for (int tq = 0; tq < 2; ++tq) {
      float mx = fmaxf(fmaxf(s4[tq][0], s4[tq][1]), fmaxf(s4[tq][2], s4[tq][3]));
      mx = fmaxf(mx, __shfl_xor(mx, 16, 64));
      mx = fmaxf(mx, __shfl_xor(mx, 32, 64));
      float mnew = fmaxf(mrow[tq], mx);
      al[tq] = __builtin_amdgcn_exp2f(mrow[tq] - mnew);
      mrow[tq] = mnew;
      float ps = 0.f;
#pragma unroll
      for (int rg = 0; rg < 4; ++rg) {
        float e = __builtin_amdgcn_exp2f(s4[tq][rg] - mnew);
        s4[tq][rg] = e;
        ps += e;
      }
      ps += __shfl_xor(ps, 16, 64);
      ps += __shfl_xor(ps, 32, 64);
      lrow[tq] = lrow[tq] * al[tq] + ps;
    }

    // ---- rescale O^T (skip when all alphas are 1 — common once m settles)
    if (!__all((al[0] == 1.f) & (al[1] == 1.f))) {
#pragma unroll
      for (int tq = 0; tq < 2; ++tq)
#pragma unroll
        for (int td = 0; td < 4; ++td)
#pragma unroll
          for (int rg = 0; rg < 4; ++rg)
            o[tq][td][rg] *= al[tq];
    }

    // ---- P in registers (B-frag of 16x16x16 == S^T C-layout)
    bf16x4 pf[2];
#pragma unroll
    for (int tq = 0; tq < 2; ++tq) {
      bf16x4 pk = { (bf16)s4[tq][0], (bf16)s4[tq][1],
                    (bf16)s4[tq][2], (bf16)s4[tq][3] };
      pf[tq] = pk;
    }

    // ---- O^T += Vt(strip) . P^T   (A = Vt b64 frags, 2-way-free banks)
#pragma unroll
    for (int td = 0; td < 4; ++td) {
      int d = td * 16 + l15;
      int uu = ((l4 >> 1) ^ ((d >> 2) & 1)) * 2 + (l4 & 1);
      bf16x4 vf = *(const bf16x4*)(&Vts[buf][d * 16 + uu * 4]);
      o[0][td] = mfma16(vf, pf[0], o[0][td]);
      o[1][td] = mfma16(vf, pf[1], o[1][td]);
    }

    buf ^= 1;
  }

  // ---- epilogue: O^T / l -> AO[q][d], b64 stores, all per-lane
#pragma unroll
  for (int tq = 0; tq < 2; ++tq) {
    float inv = 1.0f / lrow[tq];
    int q = qw + tq * 16 + l15;
#pragma unroll
    for (int td = 0; td < 4; ++td) {
      bf16x4 ok = { (bf16)(o[tq][td][0] * inv), (bf16)(o[tq][td][1] * inv),
                    (bf16)(o[tq][td][2] * inv), (bf16)(o[tq][td][3] * inv) };
      *(bf16x4*)(AO + base + (size_t)q * C + td * 16 + l4 * 4) = ok;
    }
  }
}

// ---------------- launch ----------------
extern "C" void kernel_launch(void* const* d_in, const int* in_sizes, int n_in,
                              void* d_out, int out_size, void* d_ws, size_t ws_size,
                              hipStream_t stream) {
  const float* x  = (const float*)d_in[0];
  const float* Wq = (const float*)d_in[1];
  const float* bq = (const float*)d_in[2];
  const float* Wk = (const float*)d_in[3];
  const float* bk = (const float*)d_in[4];
  const float* Wv = (const float*)d_in[5];
  const float* bv = (const float*)d_in[6];
  const float* Wo = (const float*)d_in[7];
  const float* bo = (const float*)d_in[8];

  bf16* ws = (bf16*)d_ws;
  const size_t M1 = (size_t)1 << 20;
  bf16* xb  = ws;            // 4M
  bf16* wqb = ws + 4 * M1;   // wq|wk|wv (1M each)
  bf16* wob = ws + 7 * M1;   // 1M
  bf16* Qp  = ws + 8 * M1;   // Q (4M) | K (4M)
  bf16* Vtp = ws + 16 * M1;  // Vt (4M), written by QKV gemm epilogue
  bf16* AOp = ws + 20 * M1;  // 4M

  // 1) cast inputs to bf16
  cast_all<<<8192, 256, 0, stream>>>(x, Wq, Wk, Wv, Wo, ws);
  // 2) fused QKV projection (Q pre-scaled; V written transposed to Vtp)
  gemm_bt<false, true, 128><<<dim3(24, 32), 256, 0, stream>>>(
      xb, wqb, bq, bk, bv, (void*)Qp, Vtp, 4096, 1024, 1024, 0.125f * LOG2E);
  // 3) wave-autonomous causal flash attention (2048 x 1-wave blocks)
  attn_kernel<<<2048, 64, 0, stream>>>(Qp, Qp + 4 * M1, Vtp, AOp);
  // 4) output projection (fp32 out + bias)
  gemm_bt<true, false, 64><<<dim3(16, 32), 256, 0, stream>>>(
      AOp, wob, bo, nullptr, nullptr, d_out, nullptr, 4096, 1024, 1024, 1.0f);
}

// Round 11
// 179.951 us; speedup vs baseline: 1.3722x; 1.3722x over previous
//
#include <hip/hip_runtime.h>
#include <hip/hip_bf16.h>

// MHA: B=2, T=2048, C=1024, H=16, Dh=64. fp32 in/out, bf16 MFMA internally.
// ws layout (bf16 elems): [0,4M): xb. [4M,7M): wq|wk|wv. [7M,8M): wo.
// [8M,12M): Q. [12M,16M): K. [16M,20M): Vt (written by QKV gemm epilogue).
// [20M,24M): AO.  Total 48 MB.

typedef __bf16 bf16;
typedef __attribute__((ext_vector_type(8))) __bf16 bf16x8;
typedef __attribute__((ext_vector_type(4))) __bf16 bf16x4;
typedef __attribute__((ext_vector_type(4))) float floatx4;
typedef __attribute__((ext_vector_type(4))) short short4v;

#define LOG2E 1.44269504088896340736f

__device__ __forceinline__ void gl2lds16(const void* g, void* l) {
  __builtin_amdgcn_global_load_lds((const __attribute__((address_space(1))) void*)g,
                                   (__attribute__((address_space(3))) void*)l, 16, 0, 0);
}

// 16x16x16 bf16 MFMA (k=16): B-operand layout (n=l15, k=l4*4+i) matches the
// 16x16 C/D layout exactly -> P stays in registers (verified correct in R10).
__device__ __forceinline__ floatx4 mfma16(bf16x4 a, bf16x4 b, floatx4 c) {
#if __has_builtin(__builtin_amdgcn_mfma_f32_16x16x16_bf16)
  return __builtin_amdgcn_mfma_f32_16x16x16_bf16(a, b, c, 0, 0, 0);
#elif __has_builtin(__builtin_amdgcn_mfma_f32_16x16x16bf16_1k)
  return __builtin_amdgcn_mfma_f32_16x16x16bf16_1k(
      __builtin_bit_cast(short4v, a), __builtin_bit_cast(short4v, b), c, 0, 0, 0);
#else
  floatx4 d = c;
  asm volatile("v_mfma_f32_16x16x16_bf16 %0, %1, %2, %0"
               : "+v"(d) : "v"(a), "v"(b));
  return d;
#endif
}

// ---------------- cast fp32 -> bf16 (x | wq | wk | wv | wo) ----------------
__global__ __launch_bounds__(256) void cast_all(
    const float* __restrict__ x, const float* __restrict__ wq,
    const float* __restrict__ wk, const float* __restrict__ wv,
    const float* __restrict__ wo, bf16* __restrict__ dst)
{
  const size_t M1 = (size_t)1 << 20;
  size_t i4 = ((size_t)blockIdx.x * 256 + threadIdx.x) * 4;
  const float* src = x;
  size_t off = i4;
  if (i4 >= 4 * M1) {
    size_t r = i4 - 4 * M1;
    int seg = (int)(r >> 20);
    off = r & (M1 - 1);
    src = (seg == 0) ? wq : (seg == 1) ? wk : (seg == 2) ? wv : wo;
  }
  float4 f = *(const float4*)(src + off);
  bf16x4 o = { (bf16)f.x, (bf16)f.y, (bf16)f.z, (bf16)f.w };
  *(bf16x4*)(dst + i4) = o;
}

// ---------------- GEMM: out[m][n] = sum_k A[m][k]*W[n][k] + bias[n] ----------------
// BK=64, xor-swizzled 16B LDS groups, 32 MFMA/barrier.
// QKV: mat0 -> Q (bf16, pre-scaled), mat1 -> K, mat2 -> Vt[bh][d][t].
template<bool F32OUT, bool QKV, int BN>
__global__ __launch_bounds__(256, 3) void gemm_bt(
    const bf16* __restrict__ A, const bf16* __restrict__ Wb,
    const float* __restrict__ bq, const float* __restrict__ bk,
    const float* __restrict__ bv, void* __restrict__ outb,
    bf16* __restrict__ vt, int M, int N, int K, float qscale)
{
  __shared__ bf16 As[128 * 64];
  __shared__ bf16 Bs[BN * 64];
  const int tid = threadIdx.x;
  const int lane = tid & 63;
  const int wid = tid >> 6;
  const int l15 = lane & 15, l4 = lane >> 4;
  constexpr int I = (BN == 128) ? 4 : 2;
  const int wr = (BN == 128) ? (wid >> 1) : wid;
  const int wc = (BN == 128) ? (wid & 1) : 0;

  const bf16* W;
  const float* bias;
  float osc = 1.0f;
  int n0, mat = 0;
  bf16* outh;
  float* outf;
  if (QKV) {
    mat = blockIdx.x >> 3;
    n0 = (blockIdx.x & 7) << 7;
    W = Wb + ((size_t)mat << 20);
    bias = (mat == 0) ? bq : (mat == 1 ? bk : bv);
    if (mat == 0) osc = qscale;
    outh = (bf16*)outb + ((size_t)mat << 22);
    outf = nullptr;
  } else {
    n0 = blockIdx.x * BN;
    W = Wb;
    bias = bq;
    outf = (float*)outb;
    outh = nullptr;
  }
  const int m0 = blockIdx.y << 7;

  floatx4 acc[I][4] = {};

  for (int k0 = 0; k0 < K; k0 += 64) {
#pragma unroll
    for (int it = 0; it < 4; ++it) {
      int c = it * 256 + tid;
      int row = c >> 3, gs = ((c & 7) ^ (row & 7)) << 3;
      gl2lds16(A + (size_t)(m0 + row) * K + k0 + gs, As + c * 8);
    }
#pragma unroll
    for (int it = 0; it < BN / 32; ++it) {
      int c = it * 256 + tid;
      int row = c >> 3, gs = ((c & 7) ^ (row & 7)) << 3;
      gl2lds16(W + (size_t)(n0 + row) * K + k0 + gs, Bs + c * 8);
    }
    __syncthreads();
#pragma unroll
    for (int kk = 0; kk < 2; ++kk) {
      bf16x8 af[I], bfr[4];
#pragma unroll
      for (int i = 0; i < I; ++i) {
        int r = wr * (I * 16) + i * 16 + l15;
        int g = (kk * 4 + l4) ^ (r & 7);
        af[i] = *(const bf16x8*)(As + r * 64 + g * 8);
      }
#pragma unroll
      for (int j = 0; j < 4; ++j) {
        int r = wc * 64 + j * 16 + l15;
        int g = (kk * 4 + l4) ^ (r & 7);
        bfr[j] = *(const bf16x8*)(Bs + r * 64 + g * 8);
      }
#pragma unroll
      for (int i = 0; i < I; ++i)
#pragma unroll
        for (int j = 0; j < 4; ++j)
          acc[i][j] = __builtin_amdgcn_mfma_f32_16x16x32_bf16(af[i], bfr[j], acc[i][j], 0, 0, 0);
    }
    __syncthreads();
  }

  if (QKV && mat == 2) {
#pragma unroll
    for (int j = 0; j < 4; ++j) {
      int col = n0 + wc * 64 + j * 16 + l15;
      float bv_ = bias[col];
      int h = col >> 6, d = col & 63;
#pragma unroll
      for (int i = 0; i < I; ++i) {
        int row = m0 + wr * (I * 16) + i * 16 + l4 * 4;
        int bb = row >> 11, t = row & 2047;
        bf16x4 pk;
#pragma unroll
        for (int rg = 0; rg < 4; ++rg) pk[rg] = (bf16)(acc[i][j][rg] + bv_);
        *(bf16x4*)(vt + (((size_t)(bb * 16 + h)) << 17) + ((size_t)d << 11) + t) = pk;
      }
    }
    return;
  }

#pragma unroll
  for (int j = 0; j < 4; ++j) {
    int col = n0 + wc * 64 + j * 16 + l15;
    float bv_ = bias[col];
#pragma unroll
    for (int i = 0; i < I; ++i) {
#pragma unroll
      for (int rg = 0; rg < 4; ++rg) {
        int row = m0 + wr * (I * 16) + i * 16 + l4 * 4 + rg;
        float v = (acc[i][j][rg] + bv_) * osc;
        if (F32OUT) outf[(size_t)row * N + col] = v;
        else        outh[(size_t)row * N + col] = (bf16)v;
      }
    }
  }
}

// ---------------- fused causal flash attention ----------------
// grid 1024 1-D: bh = u&31 (head-local L2/XCD), qt = 31-(u>>5) (heavy first).
// 64 q-rows/block (16/wave, Q register B-frags), K/V tiles of 64 j,
// double-buffered gl2lds staging, ONE barrier per tile. S^T (A=K, B=Q) so
// each lane owns one q-row: per-lane softmax stats (+2 shuffles each).
// PV via k=16 MFMA whose B-layout equals the S^T C-layout -> P STAYS IN
// REGISTERS, no Ps LDS. LDS 33 KB -> 4 blocks/CU (16 waves).
// Q pre-scaled by 1/sqrt(Dh)*log2e.
__global__ __launch_bounds__(256, 4) void attn_kernel(
    const bf16* __restrict__ Q, const bf16* __restrict__ Kg,
    const bf16* __restrict__ Vt, bf16* __restrict__ AO)
{
  constexpr int T = 2048, C = 1024;
  __shared__ bf16 Ks[2][64 * 64];   // [j][d], 16B groups xor'd by (j&7)
  __shared__ bf16 Vts[2][64 * 64];  // [d][j], 16B groups xor'd by (d&7)

  const int tid = threadIdx.x;
  const int lane = tid & 63;
  const int w = tid >> 6;
  const int l15 = lane & 15, l4 = lane >> 4;

  const int u = blockIdx.x;
  const int bh = u & 31;
  const int qt = 31 - (u >> 5);            // 64-row q-tile, heavy first
  const int q0 = qt << 6;
  const int nkt = qt + 1;                  // 64-j tiles
  const size_t base = ((size_t)(bh >> 4) * T) * C + (bh & 15) * 64;
  const bf16* vtb = Vt + ((size_t)bh << 17);

  auto stageK = [&](int j0, int bufi) {
#pragma unroll
    for (int it = 0; it < 2; ++it) {
      int c = it * 256 + tid;
      int row = c >> 3, g = (c & 7) ^ (row & 7);
      gl2lds16(Kg + base + (size_t)(j0 + row) * C + g * 8, &Ks[bufi][c * 8]);
    }
  };
  auto stageV = [&](int j0, int bufi) {
#pragma unroll
    for (int it = 0; it < 2; ++it) {
      int c = it * 256 + tid;
      int d = c >> 3, g = (c & 7) ^ (d & 7);
      gl2lds16(vtb + ((size_t)d << 11) + j0 + g * 8, &Vts[bufi][c * 8]);
    }
  };

  const int q = q0 + w * 16 + l15;         // this lane's q-row

  // Q B-frags in registers
  bf16x8 qf[2];
  {
    const bf16* qp = Q + base + (size_t)q * C + l4 * 8;
    qf[0] = *(const bf16x8*)(qp);
    qf[1] = *(const bf16x8*)(qp + 32);
  }

  floatx4 o[4] = {};                       // O^T: col q=l15, row d=td*16+l4*4+rg
  float mrow = -1e38f, lrow = 0.f;

  stageK(0, 0);
  stageV(0, 0);

  for (int jt = 0; jt < nkt; ++jt) {
    __syncthreads();  // staging of tile jt visible; buf jt^1 reads done
    const int cur = jt & 1;
    if (jt + 1 < nkt) {
      stageK((jt + 1) << 6, cur ^ 1);
      stageV((jt + 1) << 6, cur ^ 1);
    }
    const int j0 = jt << 6;

    // ---- S^T = K Q^T : s4[tj], row j = tj*16+l4*4+rg, col q = l15
    floatx4 s4[4] = {};
#pragma unroll
    for (int kk = 0; kk < 2; ++kk) {
#pragma unroll
      for (int tj = 0; tj < 4; ++tj) {
        int r = tj * 16 + l15;
        int g = (kk * 4 + l4) ^ (r & 7);
        bf16x8 kf = *(const bf16x8*)(&Ks[cur][r * 64 + g * 8]);
        s4[tj] = __builtin_amdgcn_mfma_f32_16x16x32_bf16(kf, qf[kk], s4[tj], 0, 0, 0);
      }
    }

    // ---- causal mask (j > q): only the last (diagonal) tile
    if (jt == nkt - 1) {
#pragma unroll
      for (int tj = 0; tj < 4; ++tj) {
        int j = j0 + tj * 16 + l4 * 4;
#pragma unroll
        for (int rg = 0; rg < 4; ++rg)
          if (j + rg > q) s4[tj][rg] = -3e38f;
      }
    }

    // ---- online softmax: lane owns row q; in-register stats + 2 shuffles
    float mx = -3e38f;
#pragma unroll
    for (int tj = 0; tj < 4; ++tj)
#pragma unroll
      for (int rg = 0; rg < 4; ++rg)
        mx = fmaxf(mx, s4[tj][rg]);
    mx = fmaxf(mx, __shfl_xor(mx, 16, 64));
    mx = fmaxf(mx, __shfl_xor(mx, 32, 64));
    float mnew = fmaxf(mrow, mx);
    float al = __builtin_amdgcn_exp2f(mrow - mnew);
    mrow = mnew;
    float ps = 0.f;
#pragma unroll
    for (int tj = 0; tj < 4; ++tj)
#pragma unroll
      for (int rg = 0; rg < 4; ++rg) {
        float e = __builtin_amdgcn_exp2f(s4[tj][rg] - mnew);
        s4[tj][rg] = e;
        ps += e;
      }
    ps += __shfl_xor(ps, 16, 64);
    ps += __shfl_xor(ps, 32, 64);
    lrow = lrow * al + ps;

    // ---- rescale O^T by alpha (per-lane); skip when wave-uniformly 1
    if (!__all(al == 1.f)) {
#pragma unroll
      for (int td = 0; td < 4; ++td)
#pragma unroll
        for (int rg = 0; rg < 4; ++rg)
          o[td][rg] *= al;
    }

    // ---- P in registers (B-frag of k=16 MFMA == S^T C-layout)
    bf16x4 pf[4];
#pragma unroll
    for (int tj = 0; tj < 4; ++tj) {
      bf16x4 pk = { (bf16)s4[tj][0], (bf16)s4[tj][1],
                    (bf16)s4[tj][2], (bf16)s4[tj][3] };
      pf[tj] = pk;
    }

    // ---- O^T += Vt P^T : A = Vt b64 frags (group-xor layout, 2-way banks)
#pragma unroll
    for (int tj = 0; tj < 4; ++tj) {
#pragma unroll
      for (int td = 0; td < 4; ++td) {
        int d = td * 16 + l15;
        int g = (tj * 2 + (l4 >> 1)) ^ (d & 7);
        bf16x4 vf = *(const bf16x4*)(&Vts[cur][d * 64 + g * 8 + (l4 & 1) * 4]);
        o[td] = mfma16(vf, pf[tj], o[td]);
      }
    }
  }

  // ---- epilogue: O^T / l -> AO[q][d], b64 stores, all per-lane
  float inv = 1.0f / lrow;
#pragma unroll
  for (int td = 0; td < 4; ++td) {
    bf16x4 ok = { (bf16)(o[td][0] * inv), (bf16)(o[td][1] * inv),
                  (bf16)(o[td][2] * inv), (bf16)(o[td][3] * inv) };
    *(bf16x4*)(AO + base + (size_t)q * C + td * 16 + l4 * 4) = ok;
  }
}

// ---------------- launch ----------------
extern "C" void kernel_launch(void* const* d_in, const int* in_sizes, int n_in,
                              void* d_out, int out_size, void* d_ws, size_t ws_size,
                              hipStream_t stream) {
  const float* x  = (const float*)d_in[0];
  const float* Wq = (const float*)d_in[1];
  const float* bq = (const float*)d_in[2];
  const float* Wk = (const float*)d_in[3];
  const float* bk = (const float*)d_in[4];
  const float* Wv = (const float*)d_in[5];
  const float* bv = (const float*)d_in[6];
  const float* Wo = (const float*)d_in[7];
  const float* bo = (const float*)d_in[8];

  bf16* ws = (bf16*)d_ws;
  const size_t M1 = (size_t)1 << 20;
  bf16* xb  = ws;            // 4M
  bf16* wqb = ws + 4 * M1;   // wq|wk|wv (1M each)
  bf16* wob = ws + 7 * M1;   // 1M
  bf16* Qp  = ws + 8 * M1;   // Q (4M) | K (4M)
  bf16* Vtp = ws + 16 * M1;  // Vt (4M), written by QKV gemm epilogue
  bf16* AOp = ws + 20 * M1;  // 4M

  // 1) cast inputs to bf16
  cast_all<<<8192, 256, 0, stream>>>(x, Wq, Wk, Wv, Wo, ws);
  // 2) fused QKV projection (Q pre-scaled; V written transposed to Vtp)
  gemm_bt<false, true, 128><<<dim3(24, 32), 256, 0, stream>>>(
      xb, wqb, bq, bk, bv, (void*)Qp, Vtp, 4096, 1024, 1024, 0.125f * LOG2E);
  // 3) causal flash attention (64q blocks, register-P, 4 blocks/CU)
  attn_kernel<<<1024, 256, 0, stream>>>(Qp, Qp + 4 * M1, Vtp, AOp);
  // 4) output projection (fp32 out + bias)
  gemm_bt<true, false, 64><<<dim3(16, 32), 256, 0, stream>>>(
      AOp, wob, bo, nullptr, nullptr, d_out, nullptr, 4096, 1024, 1024, 1.0f);
}

// Round 12
// 174.533 us; speedup vs baseline: 1.4148x; 1.0310x over previous
//
#include <hip/hip_runtime.h>
#include <hip/hip_bf16.h>

// MHA: B=2, T=2048, C=1024, H=16, Dh=64. fp32 in/out, bf16 MFMA internally.
// ws layout (bf16 elems): [0,4M): xb. [4M,7M): wq|wk|wv. [7M,8M): wo.
// [8M,12M): Q. [12M,16M): K. [16M,20M): Vt (quad-interleaved, written by
// QKV gemm epilogue). [20M,24M): AO.  Total 48 MB.

typedef __bf16 bf16;
typedef __attribute__((ext_vector_type(8))) __bf16 bf16x8;
typedef __attribute__((ext_vector_type(4))) __bf16 bf16x4;
typedef __attribute__((ext_vector_type(4))) float floatx4;
typedef __attribute__((ext_vector_type(4))) short short4v;

#define LOG2E 1.44269504088896340736f

__device__ __forceinline__ void gl2lds16(const void* g, void* l) {
  __builtin_amdgcn_global_load_lds((const __attribute__((address_space(1))) void*)g,
                                   (__attribute__((address_space(3))) void*)l, 16, 0, 0);
}

// 16x16x16 bf16 MFMA (k=16): B-operand layout (n=l15, k=l4*4+i) matches the
// 16x16 C/D layout exactly -> P stays in registers (verified R10/R11).
__device__ __forceinline__ floatx4 mfma16(bf16x4 a, bf16x4 b, floatx4 c) {
#if __has_builtin(__builtin_amdgcn_mfma_f32_16x16x16_bf16)
  return __builtin_amdgcn_mfma_f32_16x16x16_bf16(a, b, c, 0, 0, 0);
#elif __has_builtin(__builtin_amdgcn_mfma_f32_16x16x16bf16_1k)
  return __builtin_amdgcn_mfma_f32_16x16x16bf16_1k(
      __builtin_bit_cast(short4v, a), __builtin_bit_cast(short4v, b), c, 0, 0, 0);
#else
  floatx4 d = c;
  asm volatile("v_mfma_f32_16x16x16_bf16 %0, %1, %2, %0"
               : "+v"(d) : "v"(a), "v"(b));
  return d;
#endif
}

// ---------------- cast fp32 -> bf16 (x | wq | wk | wv | wo) ----------------
__global__ __launch_bounds__(256) void cast_all(
    const float* __restrict__ x, const float* __restrict__ wq,
    const float* __restrict__ wk, const float* __restrict__ wv,
    const float* __restrict__ wo, bf16* __restrict__ dst)
{
  const size_t M1 = (size_t)1 << 20;
  size_t i4 = ((size_t)blockIdx.x * 256 + threadIdx.x) * 4;
  const float* src = x;
  size_t off = i4;
  if (i4 >= 4 * M1) {
    size_t r = i4 - 4 * M1;
    int seg = (int)(r >> 20);
    off = r & (M1 - 1);
    src = (seg == 0) ? wq : (seg == 1) ? wk : (seg == 2) ? wv : wo;
  }
  float4 f = *(const float4*)(src + off);
  bf16x4 o = { (bf16)f.x, (bf16)f.y, (bf16)f.z, (bf16)f.w };
  *(bf16x4*)(dst + i4) = o;
}

// ---------------- GEMM: out[m][n] = sum_k A[m][k]*W[n][k] + bias[n] ----------------
// BK=64, xor-swizzled 16B LDS groups, 32 MFMA/barrier.
// QKV: mat0 -> Q (bf16, pre-scaled), mat1 -> K, mat2 -> Vt[bh][d][t']
// with t' quad-interleaved within each 32-t block:
//   t' = (t&~31) | quad<<3 | half<<2 | (t&3)   (quad=(t>>2)&3, half=(t>>4)&1)
// so one attn b128 read yields the P-quad for two adjacent 16-j blocks.
template<bool F32OUT, bool QKV, int BN>
__global__ __launch_bounds__(256, 3) void gemm_bt(
    const bf16* __restrict__ A, const bf16* __restrict__ Wb,
    const float* __restrict__ bq, const float* __restrict__ bk,
    const float* __restrict__ bv, void* __restrict__ outb,
    bf16* __restrict__ vt, int M, int N, int K, float qscale)
{
  __shared__ bf16 As[128 * 64];
  __shared__ bf16 Bs[BN * 64];
  const int tid = threadIdx.x;
  const int lane = tid & 63;
  const int wid = tid >> 6;
  const int l15 = lane & 15, l4 = lane >> 4;
  constexpr int I = (BN == 128) ? 4 : 2;
  const int wr = (BN == 128) ? (wid >> 1) : wid;
  const int wc = (BN == 128) ? (wid & 1) : 0;

  const bf16* W;
  const float* bias;
  float osc = 1.0f;
  int n0, mat = 0;
  bf16* outh;
  float* outf;
  if (QKV) {
    mat = blockIdx.x >> 3;
    n0 = (blockIdx.x & 7) << 7;
    W = Wb + ((size_t)mat << 20);
    bias = (mat == 0) ? bq : (mat == 1 ? bk : bv);
    if (mat == 0) osc = qscale;
    outh = (bf16*)outb + ((size_t)mat << 22);
    outf = nullptr;
  } else {
    n0 = blockIdx.x * BN;
    W = Wb;
    bias = bq;
    outf = (float*)outb;
    outh = nullptr;
  }
  const int m0 = blockIdx.y << 7;

  floatx4 acc[I][4] = {};

  for (int k0 = 0; k0 < K; k0 += 64) {
#pragma unroll
    for (int it = 0; it < 4; ++it) {
      int c = it * 256 + tid;
      int row = c >> 3, gs = ((c & 7) ^ (row & 7)) << 3;
      gl2lds16(A + (size_t)(m0 + row) * K + k0 + gs, As + c * 8);
    }
#pragma unroll
    for (int it = 0; it < BN / 32; ++it) {
      int c = it * 256 + tid;
      int row = c >> 3, gs = ((c & 7) ^ (row & 7)) << 3;
      gl2lds16(W + (size_t)(n0 + row) * K + k0 + gs, Bs + c * 8);
    }
    __syncthreads();
#pragma unroll
    for (int kk = 0; kk < 2; ++kk) {
      bf16x8 af[I], bfr[4];
#pragma unroll
      for (int i = 0; i < I; ++i) {
        int r = wr * (I * 16) + i * 16 + l15;
        int g = (kk * 4 + l4) ^ (r & 7);
        af[i] = *(const bf16x8*)(As + r * 64 + g * 8);
      }
#pragma unroll
      for (int j = 0; j < 4; ++j) {
        int r = wc * 64 + j * 16 + l15;
        int g = (kk * 4 + l4) ^ (r & 7);
        bfr[j] = *(const bf16x8*)(Bs + r * 64 + g * 8);
      }
#pragma unroll
      for (int i = 0; i < I; ++i)
#pragma unroll
        for (int j = 0; j < 4; ++j)
          acc[i][j] = __builtin_amdgcn_mfma_f32_16x16x32_bf16(af[i], bfr[j], acc[i][j], 0, 0, 0);
    }
    __syncthreads();
  }

  if (QKV && mat == 2) {
    // write Vt[bh][d][t'] (quad-interleaved t'): b64 stores, t quad-aligned
#pragma unroll
    for (int j = 0; j < 4; ++j) {
      int col = n0 + wc * 64 + j * 16 + l15;
      float bv_ = bias[col];
      int h = col >> 6, d = col & 63;
#pragma unroll
      for (int i = 0; i < I; ++i) {
        int row = m0 + wr * (I * 16) + i * 16 + l4 * 4;
        int bb = row >> 11, t = row & 2047;
        int tp = (t & ~31) | (((t >> 2) & 3) << 3) | (((t >> 4) & 1) << 2);
        bf16x4 pk;
#pragma unroll
        for (int rg = 0; rg < 4; ++rg) pk[rg] = (bf16)(acc[i][j][rg] + bv_);
        *(bf16x4*)(vt + (((size_t)(bb * 16 + h)) << 17) + ((size_t)d << 11) + tp) = pk;
      }
    }
    return;
  }

#pragma unroll
  for (int j = 0; j < 4; ++j) {
    int col = n0 + wc * 64 + j * 16 + l15;
    float bv_ = bias[col];
#pragma unroll
    for (int i = 0; i < I; ++i) {
#pragma unroll
      for (int rg = 0; rg < 4; ++rg) {
        int row = m0 + wr * (I * 16) + i * 16 + l4 * 4 + rg;
        float v = (acc[i][j][rg] + bv_) * osc;
        if (F32OUT) outf[(size_t)row * N + col] = v;
        else        outh[(size_t)row * N + col] = (bf16)v;
      }
    }
  }
}

// ---------------- fused causal flash attention ----------------
// grid 1024 1-D: bh = u&31 (head-local L2/XCD), qt = 31-(u>>5) (heavy first).
// 64 q-rows/block (16/wave, Q register B-frags), K/V tiles of 64 j,
// double-buffered gl2lds staging, ONE barrier per tile. S^T (A=K, B=Q) so
// each lane owns one q-row: per-lane softmax stats (+2 shuffles each).
// PV via k=16 MFMA (B-layout == S^T C-layout) -> P STAYS IN REGISTERS.
// Vt is quad-interleaved so V reads are b128 with the SAME bank pattern as
// K reads (0 conflicts measured) — one b128 feeds two k=16 PV MFMAs.
// LDS 33 KB -> 4 blocks/CU. Q pre-scaled by 1/sqrt(Dh)*log2e.
__global__ __launch_bounds__(256, 4) void attn_kernel(
    const bf16* __restrict__ Q, const bf16* __restrict__ Kg,
    const bf16* __restrict__ Vt, bf16* __restrict__ AO)
{
  constexpr int T = 2048, C = 1024;
  __shared__ bf16 Ks[2][64 * 64];   // [j][d], 16B groups xor'd by (j&7)
  __shared__ bf16 Vts[2][64 * 64];  // [d][j'], 16B groups xor'd by (d&7)

  const int tid = threadIdx.x;
  const int lane = tid & 63;
  const int w = tid >> 6;
  const int l15 = lane & 15, l4 = lane >> 4;

  const int u = blockIdx.x;
  const int bh = u & 31;
  const int qt = 31 - (u >> 5);            // 64-row q-tile, heavy first
  const int q0 = qt << 6;
  const int nkt = qt + 1;                  // 64-j tiles
  const size_t base = ((size_t)(bh >> 4) * T) * C + (bh & 15) * 64;
  const bf16* vtb = Vt + ((size_t)bh << 17);

  auto stageK = [&](int j0, int bufi) {
#pragma unroll
    for (int it = 0; it < 2; ++it) {
      int c = it * 256 + tid;
      int row = c >> 3, g = (c & 7) ^ (row & 7);
      gl2lds16(Kg + base + (size_t)(j0 + row) * C + g * 8, &Ks[bufi][c * 8]);
    }
  };
  auto stageV = [&](int j0, int bufi) {
#pragma unroll
    for (int it = 0; it < 2; ++it) {
      int c = it * 256 + tid;
      int d = c >> 3, g = (c & 7) ^ (d & 7);
      gl2lds16(vtb + ((size_t)d << 11) + j0 + g * 8, &Vts[bufi][c * 8]);
    }
  };

  const int q = q0 + w * 16 + l15;         // this lane's q-row

  // Q B-frags in registers
  bf16x8 qf[2];
  {
    const bf16* qp = Q + base + (size_t)q * C + l4 * 8;
    qf[0] = *(const bf16x8*)(qp);
    qf[1] = *(const bf16x8*)(qp + 32);
  }

  floatx4 o[4] = {};                       // O^T: col q=l15, row d=td*16+l4*4+rg
  float mrow = -1e38f, lrow = 0.f;

  stageK(0, 0);
  stageV(0, 0);

  for (int jt = 0; jt < nkt; ++jt) {
    __syncthreads();  // staging of tile jt visible; buf jt^1 reads done
    const int cur = jt & 1;
    if (jt + 1 < nkt) {
      stageK((jt + 1) << 6, cur ^ 1);
      stageV((jt + 1) << 6, cur ^ 1);
    }
    const int j0 = jt << 6;

    // ---- S^T = K Q^T : s4[tj], row j = tj*16+l4*4+rg, col q = l15
    floatx4 s4[4] = {};
#pragma unroll
    for (int kk = 0; kk < 2; ++kk) {
#pragma unroll
      for (int tj = 0; tj < 4; ++tj) {
        int r = tj * 16 + l15;
        int g = (kk * 4 + l4) ^ (r & 7);
        bf16x8 kf = *(const bf16x8*)(&Ks[cur][r * 64 + g * 8]);
        s4[tj] = __builtin_amdgcn_mfma_f32_16x16x32_bf16(kf, qf[kk], s4[tj], 0, 0, 0);
      }
    }

    // ---- causal mask (j > q): only the last (diagonal) tile
    if (jt == nkt - 1) {
#pragma unroll
      for (int tj = 0; tj < 4; ++tj) {
        int j = j0 + tj * 16 + l4 * 4;
#pragma unroll
        for (int rg = 0; rg < 4; ++rg)
          if (j + rg > q) s4[tj][rg] = -3e38f;
      }
    }

    // ---- online softmax: lane owns row q; in-register stats + 2 shuffles
    float mx = -3e38f;
#pragma unroll
    for (int tj = 0; tj < 4; ++tj)
#pragma unroll
      for (int rg = 0; rg < 4; ++rg)
        mx = fmaxf(mx, s4[tj][rg]);
    mx = fmaxf(mx, __shfl_xor(mx, 16, 64));
    mx = fmaxf(mx, __shfl_xor(mx, 32, 64));
    float mnew = fmaxf(mrow, mx);
    float al = __builtin_amdgcn_exp2f(mrow - mnew);
    mrow = mnew;
    float ps = 0.f;
#pragma unroll
    for (int tj = 0; tj < 4; ++tj)
#pragma unroll
      for (int rg = 0; rg < 4; ++rg) {
        float e = __builtin_amdgcn_exp2f(s4[tj][rg] - mnew);
        s4[tj][rg] = e;
        ps += e;
      }
    ps += __shfl_xor(ps, 16, 64);
    ps += __shfl_xor(ps, 32, 64);
    lrow = lrow * al + ps;

    // ---- rescale O^T by alpha (per-lane); skip when wave-uniformly 1
    if (!__all(al == 1.f)) {
#pragma unroll
      for (int td = 0; td < 4; ++td)
#pragma unroll
        for (int rg = 0; rg < 4; ++rg)
          o[td][rg] *= al;
    }

    // ---- P in registers (B-frag of k=16 MFMA == S^T C-layout)
    bf16x4 pf[4];
#pragma unroll
    for (int tj = 0; tj < 4; ++tj) {
      bf16x4 pk = { (bf16)s4[tj][0], (bf16)s4[tj][1],
                    (bf16)s4[tj][2], (bf16)s4[tj][3] };
      pf[tj] = pk;
    }

    // ---- O^T += Vt P^T : b128 V reads (K-identical bank pattern),
    //      low half -> tj=2tk, high half -> tj=2tk+1 (quad-interleaved Vt)
#pragma unroll
    for (int tk = 0; tk < 2; ++tk) {
#pragma unroll
      for (int td = 0; td < 4; ++td) {
        int r = td * 16 + l15;
        int g = (tk * 4 + l4) ^ (r & 7);
        bf16x8 vf = *(const bf16x8*)(&Vts[cur][r * 64 + g * 8]);
        bf16x4 lo = { vf[0], vf[1], vf[2], vf[3] };
        bf16x4 hi = { vf[4], vf[5], vf[6], vf[7] };
        o[td] = mfma16(lo, pf[tk * 2], o[td]);
        o[td] = mfma16(hi, pf[tk * 2 + 1], o[td]);
      }
    }
  }

  // ---- epilogue: O^T / l -> AO[q][d], b64 stores, all per-lane
  float inv = 1.0f / lrow;
#pragma unroll
  for (int td = 0; td < 4; ++td) {
    bf16x4 ok = { (bf16)(o[td][0] * inv), (bf16)(o[td][1] * inv),
                  (bf16)(o[td][2] * inv), (bf16)(o[td][3] * inv) };
    *(bf16x4*)(AO + base + (size_t)q * C + td * 16 + l4 * 4) = ok;
  }
}

// ---------------- launch ----------------
extern "C" void kernel_launch(void* const* d_in, const int* in_sizes, int n_in,
                              void* d_out, int out_size, void* d_ws, size_t ws_size,
                              hipStream_t stream) {
  const float* x  = (const float*)d_in[0];
  const float* Wq = (const float*)d_in[1];
  const float* bq = (const float*)d_in[2];
  const float* Wk = (const float*)d_in[3];
  const float* bk = (const float*)d_in[4];
  const float* Wv = (const float*)d_in[5];
  const float* bv = (const float*)d_in[6];
  const float* Wo = (const float*)d_in[7];
  const float* bo = (const float*)d_in[8];

  bf16* ws = (bf16*)d_ws;
  const size_t M1 = (size_t)1 << 20;
  bf16* xb  = ws;            // 4M
  bf16* wqb = ws + 4 * M1;   // wq|wk|wv (1M each)
  bf16* wob = ws + 7 * M1;   // 1M
  bf16* Qp  = ws + 8 * M1;   // Q (4M) | K (4M)
  bf16* Vtp = ws + 16 * M1;  // Vt (4M), quad-interleaved, from QKV epilogue
  bf16* AOp = ws + 20 * M1;  // 4M

  // 1) cast inputs to bf16
  cast_all<<<8192, 256, 0, stream>>>(x, Wq, Wk, Wv, Wo, ws);
  // 2) fused QKV projection (Q pre-scaled; V written interleaved to Vtp)
  gemm_bt<false, true, 128><<<dim3(24, 32), 256, 0, stream>>>(
      xb, wqb, bq, bk, bv, (void*)Qp, Vtp, 4096, 1024, 1024, 0.125f * LOG2E);
  // 3) causal flash attention (64q blocks, register-P, b128 V reads)
  attn_kernel<<<1024, 256, 0, stream>>>(Qp, Qp + 4 * M1, Vtp, AOp);
  // 4) output projection (fp32 out + bias)
  gemm_bt<true, false, 64><<<dim3(16, 32), 256, 0, stream>>>(
      AOp, wob, bo, nullptr, nullptr, d_out, nullptr, 4096, 1024, 1024, 1.0f);
}